// Round 1
// baseline (730.872 us; speedup 1.0000x reference)
//
#include <hip/hip_runtime.h>

#define B_ROWS 65536
#define WDIM 512
#define HDIM 8

__global__ __launch_bounds__(256, 4)
void fused_mlp_topk(const float* __restrict__ x,
                    const float* __restrict__ W1,
                    const float* __restrict__ b1,
                    const float* __restrict__ W2,
                    const float* __restrict__ b2,
                    const float* __restrict__ W3,
                    const float* __restrict__ b3,
                    float* __restrict__ out)
{
    // LDS staging: W1 kept [j][i] (8x512); W3 transposed to [k][i] (8x512) so
    // compute reads are 16B/lane stride-16B (conflict-free b128 pattern).
    __shared__ float sW1[HDIM * WDIM];
    __shared__ float sW3t[HDIM * WDIM];
    __shared__ float sb3[WDIM];
    __shared__ float sW2[HDIM * HDIM];
    __shared__ float sb1[HDIM];
    __shared__ float sb2[HDIM];

    const int tid = threadIdx.x;
    for (int i = tid; i < HDIM * WDIM; i += 256) sW1[i] = W1[i];
    for (int i = tid; i < HDIM * WDIM; i += 256) {
        int r = i >> 3, k = i & 7;           // W3 is (512,8) row-major
        sW3t[k * WDIM + r] = W3[i];
    }
    for (int i = tid; i < WDIM; i += 256) sb3[i] = b3[i];
    if (tid < HDIM * HDIM) sW2[tid] = W2[tid];
    if (tid < HDIM) { sb1[tid] = b1[tid]; sb2[tid] = b2[tid]; }
    __syncthreads();

    const int lane = tid & 63;
    const int wave_id = blockIdx.x * 4 + (tid >> 6);
    const int n_waves = gridDim.x * 4;

    const float4* sW1v = reinterpret_cast<const float4*>(sW1);
    const float4* sW3v = reinterpret_cast<const float4*>(sW3t);
    const float4* sb3v = reinterpret_cast<const float4*>(sb3);

    for (int row = wave_id; row < B_ROWS; row += n_waves) {
        // ---- load x row: lane covers cols [4l,4l+3] and [256+4l, 256+4l+3]
        const float4* xr = reinterpret_cast<const float4*>(x + (size_t)row * WDIM);
        float4 x0 = xr[lane];
        float4 x1 = xr[lane + 64];

        // ---- layer 1: 8 dots of 512, butterfly-reduced across the wave
        float part[HDIM];
        #pragma unroll
        for (int j = 0; j < HDIM; ++j) {
            float4 w0 = sW1v[j * 128 + lane];
            float4 w1 = sW1v[j * 128 + lane + 64];
            part[j] = x0.x*w0.x + x0.y*w0.y + x0.z*w0.z + x0.w*w0.w
                    + x1.x*w1.x + x1.y*w1.y + x1.z*w1.z + x1.w*w1.w;
        }
        #pragma unroll
        for (int off = 32; off > 0; off >>= 1) {
            #pragma unroll
            for (int j = 0; j < HDIM; ++j)
                part[j] += __shfl_xor(part[j], off, 64);
        }
        float h1[HDIM];
        #pragma unroll
        for (int j = 0; j < HDIM; ++j) {
            float v = part[j] + sb1[j];
            h1[j] = v > 0.f ? v : 0.f;
        }

        // ---- layer 2: 8x8, redundantly in every lane (broadcast LDS reads)
        float h2[HDIM];
        #pragma unroll
        for (int j = 0; j < HDIM; ++j) {
            float v = sb2[j];
            #pragma unroll
            for (int k = 0; k < HDIM; ++k)
                v += sW2[j * HDIM + k] * h1[k];
            h2[j] = v > 0.f ? v : 0.f;
        }

        // ---- layer 3: y = h2 . W3t[:, i] + b3, 8 outputs/lane as 2 float4
        float4 y0 = sb3v[lane];
        float4 y1 = sb3v[lane + 64];
        #pragma unroll
        for (int k = 0; k < HDIM; ++k) {
            float hk = h2[k];
            float4 w0 = sW3v[k * 128 + lane];
            float4 w1 = sW3v[k * 128 + lane + 64];
            y0.x += hk * w0.x; y0.y += hk * w0.y; y0.z += hk * w0.z; y0.w += hk * w0.w;
            y1.x += hk * w1.x; y1.y += hk * w1.y; y1.z += hk * w1.z; y1.w += hk * w1.w;
        }

        // ---- softmax (faithful fp32: exp(y - max) / sum, IEEE division)
        float m = fmaxf(fmaxf(fmaxf(y0.x, y0.y), fmaxf(y0.z, y0.w)),
                        fmaxf(fmaxf(y1.x, y1.y), fmaxf(y1.z, y1.w)));
        #pragma unroll
        for (int off = 32; off > 0; off >>= 1)
            m = fmaxf(m, __shfl_xor(m, off, 64));

        float e[8];
        e[0] = expf(y0.x - m); e[1] = expf(y0.y - m);
        e[2] = expf(y0.z - m); e[3] = expf(y0.w - m);
        e[4] = expf(y1.x - m); e[5] = expf(y1.y - m);
        e[6] = expf(y1.z - m); e[7] = expf(y1.w - m);
        float s = 0.f;
        #pragma unroll
        for (int t = 0; t < 8; ++t) s += e[t];
        #pragma unroll
        for (int off = 32; off > 0; off >>= 1)
            s += __shfl_xor(s, off, 64);

        float p[8];
        #pragma unroll
        for (int t = 0; t < 8; ++t) p[t] = e[t] / s;
        if (lane == 0)  p[0] = 1.0f;   // global col 0
        if (lane == 63) p[7] = 1.0f;   // global col 511

        // ---- 16th-largest value (with duplicate semantics): iterative
        // max-extract; exactly ONE instance removed per iteration.
        float sel[8];
        #pragma unroll
        for (int t = 0; t < 8; ++t) sel[t] = p[t];

        float thr = 0.f;
        #pragma unroll
        for (int it = 0; it < 16; ++it) {
            float lm = sel[0];
            #pragma unroll
            for (int t = 1; t < 8; ++t) lm = fmaxf(lm, sel[t]);
            float M = lm;
            #pragma unroll
            for (int off = 32; off > 0; off >>= 1)
                M = fmaxf(M, __shfl_xor(M, off, 64));
            thr = M;
            if (it < 15) {
                unsigned long long bal = __ballot(lm == M);
                int firstlane = __ffsll(bal) - 1;
                bool doit = (lane == firstlane);
                #pragma unroll
                for (int t = 0; t < 8; ++t) {
                    bool hit = doit && (sel[t] == M);
                    sel[t] = hit ? -2.0f : sel[t];
                    doit = doit && !hit;
                }
            }
        }

        // ---- emit 0/1 mask
        float4 r0, r1;
        r0.x = p[0] >= thr ? 1.f : 0.f;
        r0.y = p[1] >= thr ? 1.f : 0.f;
        r0.z = p[2] >= thr ? 1.f : 0.f;
        r0.w = p[3] >= thr ? 1.f : 0.f;
        r1.x = p[4] >= thr ? 1.f : 0.f;
        r1.y = p[5] >= thr ? 1.f : 0.f;
        r1.z = p[6] >= thr ? 1.f : 0.f;
        r1.w = p[7] >= thr ? 1.f : 0.f;
        float4* orow = reinterpret_cast<float4*>(out + (size_t)row * WDIM);
        orow[lane]      = r0;
        orow[lane + 64] = r1;
    }
}

extern "C" void kernel_launch(void* const* d_in, const int* in_sizes, int n_in,
                              void* d_out, int out_size, void* d_ws, size_t ws_size,
                              hipStream_t stream) {
    const float* x  = (const float*)d_in[0];
    const float* W1 = (const float*)d_in[1];
    const float* b1 = (const float*)d_in[2];
    const float* W2 = (const float*)d_in[3];
    const float* b2 = (const float*)d_in[4];
    const float* W3 = (const float*)d_in[5];
    const float* b3 = (const float*)d_in[6];
    float* out = (float*)d_out;

    // 1024 blocks x 256 thr = 4096 waves, 16 rows/wave, 4 blocks/CU (LDS-capped)
    fused_mlp_topk<<<dim3(1024), dim3(256), 0, stream>>>(x, W1, b1, W2, b2, W3, b3, out);
}

// Round 2
// 407.336 us; speedup vs baseline: 1.7943x; 1.7943x over previous
//
#include <hip/hip_runtime.h>
#include <math.h>

#define B_ROWS 65536
#define WDIM 512
#define HDIM 8

// ---- DPP cross-lane (VALU pipe; avoids ds_swizzle latency/contention) ----
template<int CTRL, int ROWM>
__device__ __forceinline__ float dpp_mov(float oldv, float x) {
    return __int_as_float(__builtin_amdgcn_update_dpp(
        __float_as_int(oldv), __float_as_int(x), CTRL, ROWM, 0xF, false));
}

// Full-wave (64-lane) sum, result broadcast to all lanes via readlane(63).
__device__ __forceinline__ float wave_sum(float x) {
    x += dpp_mov<0x121, 0xF>(0.f, x);   // row_ror:1
    x += dpp_mov<0x122, 0xF>(0.f, x);   // row_ror:2
    x += dpp_mov<0x124, 0xF>(0.f, x);   // row_ror:4
    x += dpp_mov<0x128, 0xF>(0.f, x);   // row_ror:8  -> every lane has its row-of-16 sum
    x += dpp_mov<0x142, 0xA>(0.f, x);   // row_bcast15 -> rows 1,3 accumulate prev row
    x += dpp_mov<0x143, 0xC>(0.f, x);   // row_bcast31 -> rows 2,3; lane63 = total
    return __int_as_float(__builtin_amdgcn_readlane(__float_as_int(x), 63));
}

__device__ __forceinline__ float wave_max(float x) {
    x = fmaxf(x, dpp_mov<0x121, 0xF>(-INFINITY, x));
    x = fmaxf(x, dpp_mov<0x122, 0xF>(-INFINITY, x));
    x = fmaxf(x, dpp_mov<0x124, 0xF>(-INFINITY, x));
    x = fmaxf(x, dpp_mov<0x128, 0xF>(-INFINITY, x));
    x = fmaxf(x, dpp_mov<0x142, 0xA>(-INFINITY, x));
    x = fmaxf(x, dpp_mov<0x143, 0xC>(-INFINITY, x));
    return __int_as_float(__builtin_amdgcn_readlane(__float_as_int(x), 63));
}

__device__ __forceinline__ float dot8(float4 a0, float4 a1, float4 b0, float4 b1) {
    float s = a0.x * b0.x;
    s = fmaf(a0.y, b0.y, s); s = fmaf(a0.z, b0.z, s); s = fmaf(a0.w, b0.w, s);
    s = fmaf(a1.x, b1.x, s); s = fmaf(a1.y, b1.y, s);
    s = fmaf(a1.z, b1.z, s); s = fmaf(a1.w, b1.w, s);
    return s;
}

__global__ __launch_bounds__(256, 4)
void fused_mlp_topk(const float* __restrict__ x,
                    const float* __restrict__ W1,
                    const float* __restrict__ b1,
                    const float* __restrict__ W2,
                    const float* __restrict__ b2,
                    const float* __restrict__ W3,
                    const float* __restrict__ b3,
                    float* __restrict__ out)
{
    // W1 as [j][i] (8x512), W3 transposed to [k][i] (8x512): compute reads are
    // 16B/lane stride-16B ds_read_b128 (conflict-free).
    __shared__ float sW1[HDIM * WDIM];
    __shared__ float sW3t[HDIM * WDIM];
    __shared__ float sb3[WDIM];

    const int tid = threadIdx.x;
    for (int i = tid; i < HDIM * WDIM; i += 256) sW1[i] = W1[i];
    for (int i = tid; i < HDIM * WDIM; i += 256) {
        int r = i >> 3, k = i & 7;          // W3 is (512,8) row-major
        sW3t[k * WDIM + r] = W3[i];
    }
    for (int i = tid; i < WDIM; i += 256) sb3[i] = b3[i];
    __syncthreads();

    const int lane = tid & 63;
    const int wave_id = blockIdx.x * 4 + (tid >> 6);
    const int n_waves = gridDim.x * 4;          // 4096: exactly 16 rows/wave

    const float4* sW1v = reinterpret_cast<const float4*>(sW1);
    const float4* sW3v = reinterpret_cast<const float4*>(sW3t);
    const float4* sb3v = reinterpret_cast<const float4*>(sb3);

    int row = wave_id;
    const float4* xr = reinterpret_cast<const float4*>(x + (size_t)row * WDIM);
    float4 x0 = xr[lane];
    float4 x1 = xr[lane + 64];

    #pragma unroll 1
    for (int it = 0; it < B_ROWS / 4096; ++it) {
        // -------- prefetch next row's x (hides HBM latency) --------
        const int nrow = row + n_waves;
        float4 nx0, nx1;
        if (it < B_ROWS / 4096 - 1) {
            const float4* nxr = reinterpret_cast<const float4*>(x + (size_t)nrow * WDIM);
            nx0 = nxr[lane];
            nx1 = nxr[lane + 64];
        }

        // -------- layer 1: 8 dots of 512; DPP wave reduction --------
        float part[HDIM];
        #pragma unroll
        for (int j = 0; j < HDIM; ++j) {
            float4 w0 = sW1v[j * 128 + lane];
            float4 w1 = sW1v[j * 128 + lane + 64];
            part[j] = dot8(x0, x1, w0, w1);
        }
        float h1[HDIM];
        #pragma unroll
        for (int j = 0; j < HDIM; ++j) {
            float s = wave_sum(part[j]) + b1[j];   // b1: uniform scalar load
            h1[j] = s > 0.f ? s : 0.f;
        }

        // -------- layer 2: 8x8, wave-uniform (scalar loads of W2/b2) --------
        float h2[HDIM];
        #pragma unroll
        for (int j = 0; j < HDIM; ++j) {
            float v = b2[j];
            #pragma unroll
            for (int k = 0; k < HDIM; ++k)
                v = fmaf(W2[j * HDIM + k], h1[k], v);
            h2[j] = v > 0.f ? v : 0.f;
        }

        // -------- layer 3: y = h2 . W3t[:, i] + b3 --------
        float4 y0 = sb3v[lane];
        float4 y1 = sb3v[lane + 64];
        #pragma unroll
        for (int k = 0; k < HDIM; ++k) {
            float hk = h2[k];
            float4 w0 = sW3v[k * 128 + lane];
            float4 w1 = sW3v[k * 128 + lane + 64];
            y0.x = fmaf(hk, w0.x, y0.x); y0.y = fmaf(hk, w0.y, y0.y);
            y0.z = fmaf(hk, w0.z, y0.z); y0.w = fmaf(hk, w0.w, y0.w);
            y1.x = fmaf(hk, w1.x, y1.x); y1.y = fmaf(hk, w1.y, y1.y);
            y1.z = fmaf(hk, w1.z, y1.z); y1.w = fmaf(hk, w1.w, y1.w);
        }

        // -------- softmax (fp32: exp(y - max) / sum) --------
        float lm = fmaxf(fmaxf(fmaxf(y0.x, y0.y), fmaxf(y0.z, y0.w)),
                         fmaxf(fmaxf(y1.x, y1.y), fmaxf(y1.z, y1.w)));
        float m = wave_max(lm);

        float e[8];
        e[0] = expf(y0.x - m); e[1] = expf(y0.y - m);
        e[2] = expf(y0.z - m); e[3] = expf(y0.w - m);
        e[4] = expf(y1.x - m); e[5] = expf(y1.y - m);
        e[6] = expf(y1.z - m); e[7] = expf(y1.w - m);
        float ls = ((e[0] + e[1]) + (e[2] + e[3])) + ((e[4] + e[5]) + (e[6] + e[7]));
        float s = wave_sum(ls);

        float p[8];
        #pragma unroll
        for (int t = 0; t < 8; ++t) p[t] = e[t] / s;
        if (lane == 0)  p[0] = 1.0f;   // global col 0
        if (lane == 63) p[7] = 1.0f;   // global col 511

        // -------- exact 16th-largest via radix binary search on float bits.
        // All p > 0 so bit patterns are order-isomorphic to values.
        // U := max bits with #{p > U} >= 16  =>  thr = bits(U+1) == a15 exactly,
        // including duplicate semantics (mask = p >= a15 matches jnp top_k thr).
        // Pure VALU (v_cmp/ballot) + SALU (bcnt/cselect): no DS ops, no chains
        // longer than ~30 cyc/round.
        unsigned U = 0u;
        for (int b = 30; b >= 0; --b) {
            const unsigned cand = U | (1u << b);
            const float cf = __uint_as_float(cand);
            int cnt = 0;
            #pragma unroll
            for (int t = 0; t < 8; ++t)
                cnt += __popcll(__ballot(p[t] > cf));
            if (cnt >= 16) U = cand;
        }
        const float thr = __uint_as_float(U + 1u);

        // -------- emit 0/1 mask --------
        float4 r0, r1;
        r0.x = p[0] >= thr ? 1.f : 0.f;
        r0.y = p[1] >= thr ? 1.f : 0.f;
        r0.z = p[2] >= thr ? 1.f : 0.f;
        r0.w = p[3] >= thr ? 1.f : 0.f;
        r1.x = p[4] >= thr ? 1.f : 0.f;
        r1.y = p[5] >= thr ? 1.f : 0.f;
        r1.z = p[6] >= thr ? 1.f : 0.f;
        r1.w = p[7] >= thr ? 1.f : 0.f;
        float4* orow = reinterpret_cast<float4*>(out + (size_t)row * WDIM);
        orow[lane]      = r0;
        orow[lane + 64] = r1;

        row = nrow;
        x0 = nx0;
        x1 = nx1;
    }
}

extern "C" void kernel_launch(void* const* d_in, const int* in_sizes, int n_in,
                              void* d_out, int out_size, void* d_ws, size_t ws_size,
                              hipStream_t stream) {
    const float* x  = (const float*)d_in[0];
    const float* W1 = (const float*)d_in[1];
    const float* b1 = (const float*)d_in[2];
    const float* W2 = (const float*)d_in[3];
    const float* b2 = (const float*)d_in[4];
    const float* W3 = (const float*)d_in[5];
    const float* b3 = (const float*)d_in[6];
    float* out = (float*)d_out;

    // 1024 blocks x 256 thr = 4096 waves; 16 rows/wave exactly; 4 blocks/CU
    // (LDS 34.6 KB/block), 16 waves/CU.
    fused_mlp_topk<<<dim3(1024), dim3(256), 0, stream>>>(x, W1, b1, W2, b2, W3, b3, out);
}